// Round 14
// baseline (382.643 us; speedup 1.0000x reference)
//
#include <hip/hip_runtime.h>
#include <hip/hip_bf16.h>

// ChebyKAN: y[b,o] = sum_{i,d} T_d(tanh(x[b,i])) * W[i,o,d]
// GEMM M=16384, N=1024, K=9216 with generated A (packed-fp16 Chebyshev recurrence).
// R10: R9 geometry (8 waves 64x64, 18 bufs, 1 barrier+counted vmcnt per chunk)
//      + hand-pipelined chunk body: B ds_reads 2 degrees ahead (3 rotating
//      bf sets), A recurrence 2 degrees ahead (3 rotating A sets), setprio
//      around each 8-MFMA group, dotanh in the deg7/8 MFMA shadow.

#define WSCALE 4096.0f
#define INV_WSCALE (1.0f/4096.0f)

typedef _Float16 f16;
typedef __fp16   hf2  __attribute__((ext_vector_type(2)));
typedef _Float16 f16x8 __attribute__((ext_vector_type(8)));
typedef float    f32x4 __attribute__((ext_vector_type(4)));
typedef float    f32x16 __attribute__((ext_vector_type(16)));

union F16x8u { hf2 h2[4]; f16x8 v8; };

// ---- kernel 1: repack cc [I][O][9] f32 -> wt, 16B-chunk-permuted so the
// GEMM's linear global_load_lds produces the conflict-free LDS layout (R5).
__global__ __launch_bounds__(256) void wt_transform(const float* __restrict__ cc,
                                                    f16* __restrict__ wt) {
  int t    = blockIdx.x * 256 + threadIdx.x;   // 294912 threads
  int j4   = t & 127;
  int grp  = t >> 7;
  int ncol = grp & 7;
  int rest = grp >> 3;
  int ic   = rest & 31;
  int d    = rest >> 5;                        // 0..8
  int u    = j4 >> 5;
  int h    = (j4 >> 4) & 1;
  int r    = j4 & 15;
  int rk   = (r >> 1) & 3;
  size_t base = (size_t)(d * 32 + ic) * 32768 + (size_t)ncol * 4096 + (size_t)j4 * 32;
#pragma unroll
  for (int v = 0; v < 4; ++v) {
    int tt = v ^ rk;
    int q  = tt & 1, kl = tt >> 1;
    int o  = ncol * 128 + u * 32 + q * 16 + r;
    int ib = ic * 32 + h * 16 + kl * 8;
    f16x8 val;
#pragma unroll
    for (int e = 0; e < 8; ++e)
      val[e] = (f16)(cc[((size_t)(ib + e) * 1024 + o) * 9 + d] * WSCALE);
    *(f16x8*)(wt + base + v * 8) = val;
  }
}

// ---- kernel 2: fused basis-gen + GEMM, 256x128 tile, 8 waves of 64m x 64n
__global__ __launch_bounds__(512, 2) void cheby_gemm(const float* __restrict__ x,
                                                     const f16* __restrict__ wt,
                                                     float* __restrict__ out) {
  __shared__ f16 bbuf[18][4096];              // 2 sets x 9 degree-bufs x 8KB = 144KB

  const int tid  = threadIdx.x;
  const int wid  = tid >> 6;                  // 0..7
  const int lane = tid & 63;
  const int lr   = lane & 31;
  const int lh   = lane >> 5;
  const int wm   = wid >> 1;                  // m-quarter 0..3
  const int wn   = wid & 1;                   // n-half 0..1
  const int mrow = blockIdx.x >> 3;           // 0..63
  const int ncol = blockIdx.x & 7;            // round-robin XCD: wt slice L2-resident
  const int m0   = mrow * 256 + wm * 64;
  const int n0   = ncol * 128 + wn * 64;
  // R2-pattern conflict-free lane term + wave n-half fold (f16 units):
  const int rbase = wn * 2048 + ((lane & 15) * 4 + ((lane >> 4) ^ ((lane >> 1) & 3))) * 8;

  // stage one 8KB degree-buf with a single global_load_lds (512 thr x 16B)
  auto stage = [&](int cn, int dn, int buf) {
    const f16* src = wt + (size_t)(dn * 32 + cn) * 32768 + (size_t)ncol * 4096;
    __builtin_amdgcn_global_load_lds(
        (const __attribute__((address_space(1))) unsigned*)(src + tid * 8),
        (__attribute__((address_space(3))) unsigned*)(&bbuf[buf][wid * 512]),
        16, 0, 0);
  };
  auto stage9 = [&](int cn, int b0) {
#pragma unroll
    for (int d = 0; d < 9; ++d) stage(cn, d, b0 + d);
  };

  f32x16 acc[2][2];                           // [mb][nb]
#pragma unroll
  for (int a = 0; a < 2; ++a)
#pragma unroll
    for (int b = 0; b < 2; ++b)
#pragma unroll
      for (int j = 0; j < 16; ++j) acc[a][b][j] = 0.f;

  const f16x8 ones  = {(f16)1,(f16)1,(f16)1,(f16)1,(f16)1,(f16)1,(f16)1,(f16)1};
  const f16x8 half8 = {(f16)0.5f,(f16)0.5f,(f16)0.5f,(f16)0.5f,
                       (f16)0.5f,(f16)0.5f,(f16)0.5f,(f16)0.5f};
  f16x8 t2v[2][2], t2n[2][2];                 // [mb][h]
  f32x4 xf[2][2][2];                          // [mb][h][half]

  auto loadx = [&](int cn) {   // 8 VMEM instrs
#pragma unroll
    for (int mb = 0; mb < 2; ++mb)
#pragma unroll
      for (int h = 0; h < 2; ++h) {
        const float* p = x + (size_t)(m0 + mb * 32 + lr) * 1024 + cn * 32 + h * 16 + lh * 8;
        xf[mb][h][0] = *(const f32x4*)p;
        xf[mb][h][1] = *(const f32x4*)(p + 4);
      }
  };
  auto dotanh = [&]() {        // xf -> t2n = 2*tanh(x) (f16 via cvt_pkrtz)
#pragma unroll
    for (int mb = 0; mb < 2; ++mb)
#pragma unroll
      for (int h = 0; h < 2; ++h) {
        float tf[8];
#pragma unroll
        for (int e = 0; e < 8; ++e) {
          float xx = (e < 4) ? xf[mb][h][0][e] : xf[mb][h][1][e - 4];
          tf[e] = 1.f - 2.f * __builtin_amdgcn_rcpf(__expf(2.f * xx) + 1.f);
        }
        F16x8u u;
#pragma unroll
        for (int p = 0; p < 4; ++p)
          u.h2[p] = __builtin_amdgcn_cvt_pkrtz(tf[2 * p], tf[2 * p + 1]);
        t2n[mb][h] = u.v8 + u.v8;   // exact x2
      }
  };

// REC: NEW = t2v * S1 - S2 (packed f16), over [2][2] frags
#define REC(NEW, S1, S2)                                                       \
  _Pragma("unroll") for (int mb = 0; mb < 2; ++mb)                             \
    _Pragma("unroll") for (int h = 0; h < 2; ++h)                              \
      NEW[mb][h] = __builtin_elementwise_fma(t2v[mb][h], S1[mb][h], -S2[mb][h]);

// LOADB: 4 B-frag b128 reads for degree DIDX of current set into BD
#define LOADB(BD, DIDX)                                                        \
  {                                                                            \
    const f16* bb = &bbuf[0][0] + sbase + (DIDX) * 4096 + rbase;               \
    _Pragma("unroll") for (int nb = 0; nb < 2; ++nb)                           \
      _Pragma("unroll") for (int h = 0; h < 2; ++h)                            \
        BD[nb][h] = *(const f16x8*)&bb[nb * 1024 + h * 512];                   \
  }

// MFMA8: 8 MFMAs (mb x nb x h) with A=AF, B=BD; setprio bracket
#define MFMA8(AF, BD)                                                          \
  {                                                                            \
    __builtin_amdgcn_s_setprio(1);                                             \
    _Pragma("unroll") for (int nb = 0; nb < 2; ++nb)                           \
      _Pragma("unroll") for (int mb = 0; mb < 2; ++mb) {                       \
        acc[mb][nb] = __builtin_amdgcn_mfma_f32_32x32x16_f16(AF[mb][0], BD[nb][0], \
                                                             acc[mb][nb], 0, 0, 0); \
        acc[mb][nb] = __builtin_amdgcn_mfma_f32_32x32x16_f16(AF[mb][1], BD[nb][1], \
                                                             acc[mb][nb], 0, 0, 0); \
      }                                                                        \
    __builtin_amdgcn_s_setprio(0);                                             \
  }

  // prologue: stage chunk0 set0, load+tanh chunk0 x
  stage9(0, 0);
  loadx(0);
  dotanh();

  f16x8 onesA[2][2];
#pragma unroll
  for (int mb = 0; mb < 2; ++mb)
#pragma unroll
    for (int h = 0; h < 2; ++h) onesA[mb][h] = ones;

  f16x8 R0[2][2], R1[2][2], R2[2][2];         // rotating A sets
  f16x8 b0[2][2], b1[2][2], b2[2][2];         // rotating B sets

  for (int c = 0; c < 32; ++c) {
    const bool lastc = (c == 31);
    const int  sbase = (c & 1) * 9 * 4096;    // this chunk's buf set (f16 units)
    const int  nbase = (1 - (c & 1)) * 9;     // next chunk's buf set index

    // prove own stage9(c) retired: after it only loadx(c) [8] was issued.
    asm volatile("s_waitcnt vmcnt(8)" ::: "memory");
    __builtin_amdgcn_s_barrier();
    if (!lastc) {
      stage9(c + 1, nbase);                   // 9 VMEM -> other set
      loadx(c + 1);                           // 8 VMEM
    }

    // adopt chunk-c tanh; seed A1 = t (exact)
#pragma unroll
    for (int mb = 0; mb < 2; ++mb)
#pragma unroll
      for (int h = 0; h < 2; ++h) {
        t2v[mb][h] = t2n[mb][h];
        R1[mb][h]  = t2v[mb][h] * half8;
      }
    LOADB(b0, 0) LOADB(b1, 1)

    // pipelined 9-degree body: LOADB(d+2) || REC(A_{d+2}) || MFMA(A_d, B_d)
    LOADB(b2, 2)  REC(R2, R1, onesA)  MFMA8(onesA, b0)   // deg0 (A2 into R2)
    LOADB(b0, 3)  REC(R0, R2, R1)     MFMA8(R1, b1)      // deg1 (A3 into R0)
    LOADB(b1, 4)  REC(R1, R0, R2)     MFMA8(R2, b2)      // deg2 (A4 into R1)
    LOADB(b2, 5)  REC(R2, R1, R0)     MFMA8(R0, b0)      // deg3 (A5 into R2)
    LOADB(b0, 6)  REC(R0, R2, R1)     MFMA8(R1, b1)      // deg4 (A6 into R0)
    LOADB(b1, 7)  REC(R1, R0, R2)     MFMA8(R2, b2)      // deg5 (A7 into R1)
    LOADB(b2, 8)  REC(R2, R1, R0)     MFMA8(R0, b0)      // deg6 (A8 into R2)
    if (!lastc) dotanh();                                // next-chunk seed in MFMA shadow
    MFMA8(R1, b1)                                        // deg7 (A7)
    MFMA8(R2, b2)                                        // deg8 (A8)
  }
#undef REC
#undef LOADB
#undef MFMA8

  // epilogue: 32x32 C/D map: col = lane&31, row = (j&3) + 8*(j>>2) + 4*(lane>>5)
#pragma unroll
  for (int mb = 0; mb < 2; ++mb)
#pragma unroll
    for (int nb = 0; nb < 2; ++nb)
#pragma unroll
      for (int j = 0; j < 16; ++j) {
        int row = m0 + mb * 32 + 4 * lh + (j & 3) + 8 * (j >> 2);
        int col = n0 + nb * 32 + lr;
        out[(size_t)row * 1024 + col] = acc[mb][nb][j] * INV_WSCALE;
      }
}

extern "C" void kernel_launch(void* const* d_in, const int* in_sizes, int n_in,
                              void* d_out, int out_size, void* d_ws, size_t ws_size,
                              hipStream_t stream) {
  const float* x  = (const float*)d_in[0];
  const float* cc = (const float*)d_in[1];
  f16*   wt  = (f16*)d_ws;                // 9*32*1024*32*2 = 18,874,368 B
  float* out = (float*)d_out;

  hipLaunchKernelGGL(wt_transform, dim3(1152), dim3(256), 0, stream, cc, wt);
  hipLaunchKernelGGL(cheby_gemm, dim3(512), dim3(512), 0, stream, x, wt, out);
}

// Round 16
// 328.633 us; speedup vs baseline: 1.1643x; 1.1643x over previous
//
#include <hip/hip_runtime.h>
#include <hip/hip_bf16.h>

// ChebyKAN: y[b,o] = sum_{i,d} T_d(tanh(x[b,i])) * W[i,o,d]
// GEMM M=16384, N=1024, K=9216 with generated A (packed-fp16 Chebyshev recurrence).
// R12: R11 (tanh hoisted to t2 pass) with the chunk-skew bug fixed: adopt
//      t2v = t2n BEFORE issuing loadx(c+1) (which overwrites t2n in-place).
//      R11 consumed chunk c+1's tanh in chunk c -> absmax 5e-2.

#define WSCALE 4096.0f
#define INV_WSCALE (1.0f/4096.0f)

typedef _Float16 f16;
typedef __fp16   hf2  __attribute__((ext_vector_type(2)));
typedef _Float16 f16x8 __attribute__((ext_vector_type(8)));
typedef float    f32x4 __attribute__((ext_vector_type(4)));
typedef float    f32x16 __attribute__((ext_vector_type(16)));

union F16x8u { hf2 h2[4]; f16x8 v8; };

// ---- kernel 1: repack cc [I][O][9] f32 -> wt, 16B-chunk-permuted so the
// GEMM's linear global_load_lds produces the conflict-free LDS layout (R5).
__global__ __launch_bounds__(256) void wt_transform(const float* __restrict__ cc,
                                                    f16* __restrict__ wt) {
  int t    = blockIdx.x * 256 + threadIdx.x;   // 294912 threads
  int j4   = t & 127;
  int grp  = t >> 7;
  int ncol = grp & 7;
  int rest = grp >> 3;
  int ic   = rest & 31;
  int d    = rest >> 5;                        // 0..8
  int u    = j4 >> 5;
  int h    = (j4 >> 4) & 1;
  int r    = j4 & 15;
  int rk   = (r >> 1) & 3;
  size_t base = (size_t)(d * 32 + ic) * 32768 + (size_t)ncol * 4096 + (size_t)j4 * 32;
#pragma unroll
  for (int v = 0; v < 4; ++v) {
    int tt = v ^ rk;
    int q  = tt & 1, kl = tt >> 1;
    int o  = ncol * 128 + u * 32 + q * 16 + r;
    int ib = ic * 32 + h * 16 + kl * 8;
    f16x8 val;
#pragma unroll
    for (int e = 0; e < 8; ++e)
      val[e] = (f16)(cc[((size_t)(ib + e) * 1024 + o) * 9 + d] * WSCALE);
    *(f16x8*)(wt + base + v * 8) = val;
  }
}

// ---- kernel 1b: t2 = 2*tanh(x) as f16 (bit-identical to the in-GEMM version)
__global__ __launch_bounds__(256) void t2_transform(const float* __restrict__ x,
                                                    f16* __restrict__ t2) {
  size_t gid = (size_t)blockIdx.x * 256 + threadIdx.x;   // 2,097,152 threads
  const float* p = x + gid * 8;
  f32x4 a = *(const f32x4*)p;
  f32x4 b = *(const f32x4*)(p + 4);
  float tf[8];
#pragma unroll
  for (int e = 0; e < 8; ++e) {
    float xx = (e < 4) ? a[e] : b[e - 4];
    tf[e] = 1.f - 2.f * __builtin_amdgcn_rcpf(__expf(2.f * xx) + 1.f);
  }
  F16x8u u;
#pragma unroll
  for (int q = 0; q < 4; ++q)
    u.h2[q] = __builtin_amdgcn_cvt_pkrtz(tf[2 * q], tf[2 * q + 1]);
  f16x8 v = u.v8 + u.v8;       // exact x2 in f16
  *(f16x8*)(t2 + gid * 8) = v;
}

// ---- kernel 2: fused basis-gen + GEMM, 256x128 tile, 8 waves of 64m x 64n
// PRET=1: t2 precomputed; PRET=0: in-GEMM tanh fallback (R9 path).
template <int PRET>
__global__ __launch_bounds__(512, 2) void cheby_gemm(const float* __restrict__ x,
                                                     const f16* __restrict__ t2g,
                                                     const f16* __restrict__ wt,
                                                     float* __restrict__ out) {
  __shared__ f16 bbuf[18][4096];              // 2 sets x 9 degree-bufs x 8KB = 144KB

  const int tid  = threadIdx.x;
  const int wid  = tid >> 6;                  // 0..7
  const int lane = tid & 63;
  const int lr   = lane & 31;
  const int lh   = lane >> 5;
  const int wm   = wid >> 1;                  // m-quarter 0..3
  const int wn   = wid & 1;                   // n-half 0..1
  const int mrow = blockIdx.x >> 3;           // 0..63
  const int ncol = blockIdx.x & 7;            // round-robin XCD: wt slice L2-resident
  const int m0   = mrow * 256 + wm * 64;
  const int n0   = ncol * 128 + wn * 64;
  // R2-pattern conflict-free lane term + wave n-half fold (f16 units):
  const int rbase = wn * 2048 + ((lane & 15) * 4 + ((lane >> 4) ^ ((lane >> 1) & 3))) * 8;

  // stage one 8KB degree-buf with a single global_load_lds (512 thr x 16B)
  auto stage = [&](int cn, int dn, int buf) {
    const f16* src = wt + (size_t)(dn * 32 + cn) * 32768 + (size_t)ncol * 4096;
    __builtin_amdgcn_global_load_lds(
        (const __attribute__((address_space(1))) unsigned*)(src + tid * 8),
        (__attribute__((address_space(3))) unsigned*)(&bbuf[buf][wid * 512]),
        16, 0, 0);
  };
  auto stage9 = [&](int cn, int b0) {
#pragma unroll
    for (int d = 0; d < 9; ++d) stage(cn, d, b0 + d);
  };

  f32x16 acc[2][2];                           // [mb][nb]
#pragma unroll
  for (int a = 0; a < 2; ++a)
#pragma unroll
    for (int b = 0; b < 2; ++b)
#pragma unroll
      for (int j = 0; j < 16; ++j) acc[a][b][j] = 0.f;

  const f16x8 ones  = {(f16)1,(f16)1,(f16)1,(f16)1,(f16)1,(f16)1,(f16)1,(f16)1};
  const f16x8 half8 = {(f16)0.5f,(f16)0.5f,(f16)0.5f,(f16)0.5f,
                       (f16)0.5f,(f16)0.5f,(f16)0.5f,(f16)0.5f};
  f16x8 t2v[2][2], t2n[2][2];                 // [mb][h]
  f32x4 xf[2][2][2];                          // fallback only

  auto loadx = [&](int cn) {   // PRET: 4 VMEM f16x8; else 8 VMEM f32x4
    if constexpr (PRET) {
#pragma unroll
      for (int mb = 0; mb < 2; ++mb)
#pragma unroll
        for (int h = 0; h < 2; ++h)
          t2n[mb][h] = *(const f16x8*)(t2g + (size_t)(m0 + mb * 32 + lr) * 1024
                                           + cn * 32 + h * 16 + lh * 8);
    } else {
#pragma unroll
      for (int mb = 0; mb < 2; ++mb)
#pragma unroll
        for (int h = 0; h < 2; ++h) {
          const float* p = x + (size_t)(m0 + mb * 32 + lr) * 1024 + cn * 32 + h * 16 + lh * 8;
          xf[mb][h][0] = *(const f32x4*)p;
          xf[mb][h][1] = *(const f32x4*)(p + 4);
        }
    }
  };
  auto dotanh = [&]() {        // fallback only: xf -> t2n
    if constexpr (!PRET) {
#pragma unroll
      for (int mb = 0; mb < 2; ++mb)
#pragma unroll
        for (int h = 0; h < 2; ++h) {
          float tf[8];
#pragma unroll
          for (int e = 0; e < 8; ++e) {
            float xx = (e < 4) ? xf[mb][h][0][e] : xf[mb][h][1][e - 4];
            tf[e] = 1.f - 2.f * __builtin_amdgcn_rcpf(__expf(2.f * xx) + 1.f);
          }
          F16x8u u;
#pragma unroll
          for (int q = 0; q < 4; ++q)
            u.h2[q] = __builtin_amdgcn_cvt_pkrtz(tf[2 * q], tf[2 * q + 1]);
          t2n[mb][h] = u.v8 + u.v8;
        }
    }
  };

#define REC(NEW, S1, S2)                                                       \
  _Pragma("unroll") for (int mb = 0; mb < 2; ++mb)                             \
    _Pragma("unroll") for (int h = 0; h < 2; ++h)                              \
      NEW[mb][h] = __builtin_elementwise_fma(t2v[mb][h], S1[mb][h], -S2[mb][h]);

#define CLUSTER(AF, DIDX)                                                      \
  {                                                                            \
    const f16* bb = &bbuf[0][0] + sbase + (DIDX) * 4096 + rbase;               \
    f16x8 bf[2][2];                                                            \
    _Pragma("unroll") for (int nb = 0; nb < 2; ++nb)                           \
      _Pragma("unroll") for (int h = 0; h < 2; ++h)                            \
        bf[nb][h] = *(const f16x8*)&bb[nb * 1024 + h * 512];                   \
    _Pragma("unroll") for (int nb = 0; nb < 2; ++nb)                           \
      _Pragma("unroll") for (int mb = 0; mb < 2; ++mb) {                       \
        acc[mb][nb] = __builtin_amdgcn_mfma_f32_32x32x16_f16(AF[mb][0], bf[nb][0], \
                                                             acc[mb][nb], 0, 0, 0); \
        acc[mb][nb] = __builtin_amdgcn_mfma_f32_32x32x16_f16(AF[mb][1], bf[nb][1], \
                                                             acc[mb][nb], 0, 0, 0); \
      }                                                                        \
  }

  // prologue: stage chunk0 set0, load (+tanh) chunk0
  stage9(0, 0);
  loadx(0);
  dotanh();

  f16x8 onesA[2][2];
#pragma unroll
  for (int mb = 0; mb < 2; ++mb)
#pragma unroll
    for (int h = 0; h < 2; ++h) onesA[mb][h] = ones;

  for (int c = 0; c < 32; ++c) {
    const bool lastc = (c == 31);
    const int  sbase = (c & 1) * 9 * 4096;    // this chunk's buf set (f16 units)
    const int  nbase = (1 - (c & 1)) * 9;     // next chunk's buf set index

    // prove own stage9(c) retired: only loadx(c) [PRET?4:8] was issued after it.
    if constexpr (PRET) asm volatile("s_waitcnt vmcnt(4)" ::: "memory");
    else                asm volatile("s_waitcnt vmcnt(8)" ::: "memory");
    __builtin_amdgcn_s_barrier();

    // ADOPT chunk-c t2 BEFORE loadx(c+1) overwrites t2n (R11 bug fix)
    f16x8 A1[2][2], A2[2][2], A3[2][2], A4[2][2], A5[2][2], A6[2][2], A7[2][2], A8[2][2];
#pragma unroll
    for (int mb = 0; mb < 2; ++mb)
#pragma unroll
      for (int h = 0; h < 2; ++h) {
        t2v[mb][h] = t2n[mb][h];
        A1[mb][h]  = t2v[mb][h] * half8;
      }

    if (!lastc) {
      stage9(c + 1, nbase);                   // 9 VMEM -> other set
      loadx(c + 1);
    }

    CLUSTER(onesA, 0)
    CLUSTER(A1, 1)
    REC(A2, A1, onesA)  CLUSTER(A2, 2)
    REC(A3, A2, A1)     CLUSTER(A3, 3)
    REC(A4, A3, A2)     CLUSTER(A4, 4)
    REC(A5, A4, A3)     CLUSTER(A5, 5)
    REC(A6, A5, A4)     CLUSTER(A6, 6)
    REC(A7, A6, A5)     CLUSTER(A7, 7)
    REC(A8, A7, A6)     CLUSTER(A8, 8)

    if (!lastc) dotanh();                     // fallback only
  }
#undef REC
#undef CLUSTER

  // epilogue: 32x32 C/D map: col = lane&31, row = (j&3) + 8*(j>>2) + 4*(lane>>5)
#pragma unroll
  for (int mb = 0; mb < 2; ++mb)
#pragma unroll
    for (int nb = 0; nb < 2; ++nb)
#pragma unroll
      for (int j = 0; j < 16; ++j) {
        int row = m0 + mb * 32 + 4 * lh + (j & 3) + 8 * (j >> 2);
        int col = n0 + nb * 32 + lr;
        out[(size_t)row * 1024 + col] = acc[mb][nb][j] * INV_WSCALE;
      }
}

extern "C" void kernel_launch(void* const* d_in, const int* in_sizes, int n_in,
                              void* d_out, int out_size, void* d_ws, size_t ws_size,
                              hipStream_t stream) {
  const float* x  = (const float*)d_in[0];
  const float* cc = (const float*)d_in[1];
  f16*   wt  = (f16*)d_ws;                        // 18,874,368 B
  f16*   t2  = (f16*)((char*)d_ws + 18874368);    // 33,554,432 B
  float* out = (float*)d_out;

  hipLaunchKernelGGL(wt_transform, dim3(1152), dim3(256), 0, stream, cc, wt);
  if (ws_size >= 52428800) {
    hipLaunchKernelGGL(t2_transform, dim3(8192), dim3(256), 0, stream, x, t2);
    hipLaunchKernelGGL((cheby_gemm<1>), dim3(512), dim3(512), 0, stream, x, t2, wt, out);
  } else {
    hipLaunchKernelGGL((cheby_gemm<0>), dim3(512), dim3(512), 0, stream, x, t2, wt, out);
  }
}